// Round 8
// baseline (106.216 us; speedup 1.0000x reference)
//
#include <hip/hip_runtime.h>

constexpr int NL = 256;   // lights
constexpr int HW = 256;   // H == W
constexpr int GS = 66;    // accel grid cells per side
constexpr int NCELL = GS * GS;
constexpr float RGRID = 4.125f;   // grid covers [-RGRID, RGRID]^2
constexpr int KCAND = 32;         // max candidates per cell

// 8-byte value with 4-byte alignment (x-pair load)
struct __attribute__((aligned(4))) F2 { float a, b; };

// ---- pass 0: conservative top-3 candidate lists per cell (proven round 3) ----
__global__ __launch_bounds__(256)
void build_grid(const float* __restrict__ lpos,
                unsigned char* __restrict__ cand,
                int* __restrict__ cnt)
{
    __shared__ float2 s_lp[NL];
    for (int i = threadIdx.x; i < NL; i += 256)
        s_lp[i] = reinterpret_cast<const float2*>(lpos)[i];
    __syncthreads();

    int cell = blockIdx.x * 256 + threadIdx.x;
    if (cell >= NCELL) return;
    const float CELLW = 2.f * RGRID / GS;
    float cx = -RGRID + ((cell % GS) + 0.5f) * CELLW;
    float cy = -RGRID + ((cell / GS) + 0.5f) * CELLW;

    float d0 = INFINITY, d1 = INFINITY, d2 = INFINITY;
    for (int i = 0; i < NL; ++i) {
        float dx = cx - s_lp[i].x, dy = cy - s_lp[i].y;
        float d = dx * dx + dy * dy;
        float n0 = fminf(d0, d), m0 = fmaxf(d0, d); d0 = n0;
        float n1 = fminf(d1, m0), m1 = fmaxf(d1, m0); d1 = n1;
        d2 = fminf(d2, m1);
    }
    float r = 0.70710678f * CELLW;
    float bnd = sqrtf(d2) + 2.f * r + 1e-4f;   // +eps: cell-assign ulp insurance
    bnd *= bnd;

    unsigned char* dst = cand + (size_t)cell * KCAND;
    int n = 0;
    for (int i = 0; i < NL; ++i) {             // ascending -> tie-stable order
        float dx = cx - s_lp[i].x, dy = cy - s_lp[i].y;
        float d = dx * dx + dy * dy;
        if (d <= bnd) {
            if (n < KCAND) dst[n] = (unsigned char)i;
            ++n;
        }
    }
    cnt[cell] = n;   // n > KCAND => sentinel: full scan
}

// ---- main: 2 threads per point (row split), grid-accelerated scan ----
template<bool USE_GRID>
__global__ __launch_bounds__(256, 8)
void lsf_kernel(const float* __restrict__ X,
                const float* __restrict__ shots,
                const float* __restrict__ lpos,
                const unsigned char* __restrict__ cand,
                const int* __restrict__ cnt,
                float* __restrict__ out, int B)
{
    __shared__ float2 s_lp[NL];
    for (int i = threadIdx.x; i < NL; i += 256)
        s_lp[i] = reinterpret_cast<const float2*>(lpos)[i];
    __syncthreads();

    int tid = blockIdx.x * 256 + threadIdx.x;
    int p   = tid >> 1;        // point index
    int h   = tid & 1;         // 0 -> row y0, 1 -> row y1
    if (p >= B) return;

    float4 xv = reinterpret_cast<const float4*>(X)[p];
    float qx = xv.z, qy = xv.w;

    // ---- top-3 nearest (exact semantics, ties -> lower index) ----
    float dd0 = INFINITY, dd1 = INFINITY, dd2 = INFINITY;
    int i0 = 0, i1 = 0, i2 = 0;
    auto visit = [&](int idx) {
        float2 lp = s_lp[idx];
        float dx = qx - lp.x, dy = qy - lp.y;
        float d = dx * dx + dy * dy;
        bool c0 = d < dd0, c1 = d < dd1, c2 = d < dd2;
        dd2 = c1 ? dd1 : (c2 ? d : dd2);
        i2  = c1 ? i1  : (c2 ? idx : i2);
        dd1 = c0 ? dd0 : (c1 ? d : dd1);
        i1  = c0 ? i0  : (c1 ? idx : i1);
        dd0 = c0 ? d   : dd0;
        i0  = c0 ? idx : i0;
    };

    bool full = true;
    if constexpr (USE_GRID) {
        if (fabsf(qx) <= RGRID && fabsf(qy) <= RGRID) {
            const float CELLW = 2.f * RGRID / GS;
            int cxi = min((int)((qx + RGRID) / CELLW), GS - 1);
            int cyi = min((int)((qy + RGRID) / CELLW), GS - 1);
            int cell = cyi * GS + cxi;
            int nn = cnt[cell];
            if (nn <= KCAND) {
                const uint4* lp32 =
                    reinterpret_cast<const uint4*>(cand + (size_t)cell * KCAND);
                uint4 L0 = lp32[0], L1 = lp32[1];
#define STEP(WV, BASE, BB) \
                if ((BASE) + (BB) < nn) { int ix = ((WV) >> ((BB) * 8)) & 255; visit(ix); }
#define PROCW(WV, BASE) \
                if ((BASE) < nn) { STEP(WV, BASE, 0) STEP(WV, BASE, 1) STEP(WV, BASE, 2) STEP(WV, BASE, 3) }
                PROCW(L0.x, 0)  PROCW(L0.y, 4)  PROCW(L0.z, 8)  PROCW(L0.w, 12)
                PROCW(L1.x, 16) PROCW(L1.y, 20) PROCW(L1.z, 24) PROCW(L1.w, 28)
#undef PROCW
#undef STEP
                full = false;
            }
        }
    }
    if (full) {
        #pragma unroll 4
        for (int i = 0; i < NL; ++i) visit(i);
    }

    // ---- barycentric weights (branchless fallback; NaN -> fallback) ----
    float2 p0 = s_lp[i0], p1 = s_lp[i1], p2c = s_lp[i2];
    float v0x = p1.x - p0.x,  v0y = p1.y - p0.y;
    float v1x = p2c.x - p0.x, v1y = p2c.y - p0.y;
    float v2x = qx - p0.x,    v2y = qy - p0.y;
    float d00 = v0x * v0x + v0y * v0y;
    float d11 = v1x * v1x + v1y * v1y;
    float d01 = v0x * v1x + v0y * v1y;
    float d20 = v2x * v0x + v2y * v0y;
    float d21 = v2x * v1x + v2y * v1y;
    float denom = d00 * d11 - d01 * d01;
    float v = (d11 * d20 - d01 * d21) / denom;
    float w = (d00 * d21 - d01 * d20) / denom;
    float u = 1.0f - v - w;
    bool inside = (u >= 0.f) & (v >= 0.f) & (w >= 0.f);
    float t = fminf(fmaxf(d20 / d00, 0.f), 1.f);
    float w0 = inside ? u : (1.f - t);
    float w1 = inside ? v : t;
    float w2 = inside ? w : 0.f;

    // ---- bilinear coords; this thread handles one row ----
    float px = fminf(fmaxf((xv.x + 1.f) * 0.5f * (HW - 1), 0.f), (float)(HW - 1));
    float py = fminf(fmaxf((xv.y + 1.f) * 0.5f * (HW - 1), 0.f), (float)(HW - 1));
    int x0 = (int)floorf(px), y0 = (int)floorf(py);
    int y1 = min(y0 + 1, HW - 1);
    float wx = px - (float)x0, wy = py - (float)y0;
    int  xe  = min(x0, HW - 2);
    bool xhi = (x0 == HW - 1);
    int   row = h ? y1 : y0;
    float rw  = h ? wy : (1.f - wy);

    // ---- gather: 9 x-pair loads (one row), all issued, then fence ----
    int idx3[3] = { i0, i1, i2 };
    F2 G[9];
    #pragma unroll
    for (int k = 0; k < 3; ++k) {
        unsigned lo = (unsigned)(idx3[k] * 3) << 16;   // light base (elements)
        #pragma unroll
        for (int c = 0; c < 3; ++c) {
            unsigned off = lo + ((unsigned)c << 16) + (unsigned)(row * HW + xe);
            G[k * 3 + c] = *reinterpret_cast<const F2*>(shots + off);
        }
    }
    __builtin_amdgcn_sched_barrier(0);   // keep all 9 loads in flight together

    float wk3[3] = { w0, w1, w2 };
    float s0 = 0.f, s1 = 0.f, s2 = 0.f;
    #pragma unroll
    for (int k = 0; k < 3; ++k) {
        float r0 = (xhi ? G[k*3+0].b : G[k*3+0].a) * (1.f - wx) + G[k*3+0].b * wx;
        float r1 = (xhi ? G[k*3+1].b : G[k*3+1].a) * (1.f - wx) + G[k*3+1].b * wx;
        float r2 = (xhi ? G[k*3+2].b : G[k*3+2].a) * (1.f - wx) + G[k*3+2].b * wx;
        s0 += wk3[k] * r0;
        s1 += wk3[k] * r1;
        s2 += wk3[k] * r2;
    }
    s0 *= rw; s1 *= rw; s2 *= rw;

    // ---- pair-combine rows, even lane writes ----
    float t0 = s0 + __shfl_xor(s0, 1);
    float t1 = s1 + __shfl_xor(s1, 1);
    float t2 = s2 + __shfl_xor(s2, 1);
    if (h == 0) {
        out[(size_t)p * 3 + 0] = t0;
        out[(size_t)p * 3 + 1] = t1;
        out[(size_t)p * 3 + 2] = t2;
    }
}

extern "C" void kernel_launch(void* const* d_in, const int* in_sizes, int n_in,
                              void* d_out, int out_size, void* d_ws, size_t ws_size,
                              hipStream_t stream) {
    const float* X     = (const float*)d_in[0];
    const float* shots = (const float*)d_in[1];
    const float* lpos  = (const float*)d_in[2];
    float* out = (float*)d_out;
    int B = in_sizes[0] / 4;
    long long T = 2LL * B;                 // 2 threads per point
    int grid = (int)((T + 255) / 256);

    size_t cand_bytes = (size_t)NCELL * KCAND;
    size_t need = cand_bytes + (size_t)NCELL * sizeof(int);
    if (ws_size >= need) {
        unsigned char* cand = (unsigned char*)d_ws;
        int* cnt = (int*)((char*)d_ws + cand_bytes);
        build_grid<<<(NCELL + 255) / 256, 256, 0, stream>>>(lpos, cand, cnt);
        lsf_kernel<true><<<grid, 256, 0, stream>>>(X, shots, lpos, cand, cnt, out, B);
    } else {
        lsf_kernel<false><<<grid, 256, 0, stream>>>(X, shots, lpos,
                                                    nullptr, nullptr, out, B);
    }
}

// Round 9
// 83.537 us; speedup vs baseline: 1.2715x; 1.2715x over previous
//
#include <hip/hip_runtime.h>

constexpr int NL = 256;   // lights
constexpr int HW = 256;   // H == W

// 8-byte value with 4-byte alignment (x-pair load, same 64B line ~94% of time)
struct __attribute__((aligned(4))) F2 { float a, b; };

__global__ __launch_bounds__(256, 8)
void lsf_kernel(const float* __restrict__ X,
                const float* __restrict__ shots,
                const float* __restrict__ lpos,
                float* __restrict__ out, int B)
{
    __shared__ float2 s_lp[NL];
    for (int i = threadIdx.x; i < NL; i += 256)
        s_lp[i] = reinterpret_cast<const float2*>(lpos)[i];
    __syncthreads();

    int tid = blockIdx.x * 256 + threadIdx.x;
    int p   = tid >> 1;        // point index
    int h   = tid & 1;         // half: 0 -> lights [0,128) + row y0, 1 -> rest
    if (p >= B) return;

    float4 xv = reinterpret_cast<const float4*>(X)[p];
    float qx = xv.z, qy = xv.w;

    // ---- half-scan: top-3 of my 128 lights (strict <, ties -> lower idx) ----
    float dd0 = INFINITY, dd1 = INFINITY, dd2 = INFINITY;
    int i0 = 0, i1 = 0, i2 = 0;
    auto visit = [&](float d, int idx) {
        bool c0 = d < dd0, c1 = d < dd1, c2 = d < dd2;
        dd2 = c1 ? dd1 : (c2 ? d : dd2);
        i2  = c1 ? i1  : (c2 ? idx : i2);
        dd1 = c0 ? dd0 : (c1 ? d : dd1);
        i1  = c0 ? i0  : (c1 ? idx : i1);
        dd0 = c0 ? d   : dd0;
        i0  = c0 ? idx : i0;
    };
    int base = h * (NL / 2);
    #pragma unroll 4
    for (int i = base; i < base + NL / 2; ++i) {
        float2 lp = s_lp[i];
        float dx = qx - lp.x, dy = qy - lp.y;
        visit(dx * dx + dy * dy, i);
    }

    // ---- pair-merge: exchange triples, insert high-half into low-half ----
    float ad0 = __shfl_xor(dd0, 1), ad1 = __shfl_xor(dd1, 1), ad2 = __shfl_xor(dd2, 1);
    int   ai0 = __shfl_xor(i0, 1),  ai1 = __shfl_xor(i1, 1),  ai2 = __shfl_xor(i2, 1);
    // low list = the one covering lights [0,128)  (owned by h==0)
    float hd0 = h ? dd0 : ad0, hd1 = h ? dd1 : ad1, hd2 = h ? dd2 : ad2;
    int   hi0 = h ? i0  : ai0, hi1 = h ? i1  : ai1, hi2 = h ? i2  : ai2;
    float ld0 = h ? ad0 : dd0, ld1 = h ? ad1 : dd1, ld2 = h ? ad2 : dd2;
    int   li0 = h ? ai0 : i0,  li1 = h ? ai1 : i1,  li2 = h ? ai2 : i2;
    dd0 = ld0; dd1 = ld1; dd2 = ld2; i0 = li0; i1 = li1; i2 = li2;
    visit(hd0, hi0);   // strict <  => equal dist keeps low-half (lower index)
    visit(hd1, hi1);
    visit(hd2, hi2);

    // ---- bilinear coords; this thread handles one row ----
    float px = fminf(fmaxf((xv.x + 1.f) * 0.5f * (HW - 1), 0.f), (float)(HW - 1));
    float py = fminf(fmaxf((xv.y + 1.f) * 0.5f * (HW - 1), 0.f), (float)(HW - 1));
    int x0 = (int)floorf(px), y0 = (int)floorf(py);
    int y1 = min(y0 + 1, HW - 1);
    float wx = px - (float)x0, wy = py - (float)y0;
    int  xe  = min(x0, HW - 2);
    bool xhi = (x0 == HW - 1);
    int   row = h ? y1 : y0;
    float rw  = h ? wy : (1.f - wy);

    // ---- gather: issue all 9 loads FIRST, weight math hides under them ----
    int idx3[3] = { i0, i1, i2 };
    F2 G[9];
    #pragma unroll
    for (int k = 0; k < 3; ++k) {
        unsigned lo = (unsigned)(idx3[k] * 3) << 16;   // light base (elements)
        #pragma unroll
        for (int c = 0; c < 3; ++c) {
            unsigned off = lo + ((unsigned)c << 16) + (unsigned)(row * HW + xe);
            G[k * 3 + c] = *reinterpret_cast<const F2*>(shots + off);
        }
    }
    __builtin_amdgcn_sched_barrier(0);   // all 9 loads issued; nothing sinks above

    // ---- barycentric weights (branchless fallback; NaN -> fallback) ----
    // computed AFTER load issue: ~2 divides + 25 VALU execute under vmem shadow
    float2 p0 = s_lp[i0], p1 = s_lp[i1], p2c = s_lp[i2];
    float v0x = p1.x - p0.x,  v0y = p1.y - p0.y;
    float v1x = p2c.x - p0.x, v1y = p2c.y - p0.y;
    float v2x = qx - p0.x,    v2y = qy - p0.y;
    float d00 = v0x * v0x + v0y * v0y;
    float d11 = v1x * v1x + v1y * v1y;
    float d01 = v0x * v1x + v0y * v1y;
    float d20 = v2x * v0x + v2y * v0y;
    float d21 = v2x * v1x + v2y * v1y;
    float denom = d00 * d11 - d01 * d01;
    float v = (d11 * d20 - d01 * d21) / denom;
    float w = (d00 * d21 - d01 * d20) / denom;
    float u = 1.0f - v - w;
    bool inside = (u >= 0.f) & (v >= 0.f) & (w >= 0.f);
    float t = fminf(fmaxf(d20 / d00, 0.f), 1.f);
    float w0 = inside ? u : (1.f - t);
    float w1 = inside ? v : t;
    float w2 = inside ? w : 0.f;

    float wk3[3] = { w0, w1, w2 };
    float s0 = 0.f, s1 = 0.f, s2 = 0.f;
    #pragma unroll
    for (int k = 0; k < 3; ++k) {
        float r0 = (xhi ? G[k*3+0].b : G[k*3+0].a) * (1.f - wx) + G[k*3+0].b * wx;
        float r1 = (xhi ? G[k*3+1].b : G[k*3+1].a) * (1.f - wx) + G[k*3+1].b * wx;
        float r2 = (xhi ? G[k*3+2].b : G[k*3+2].a) * (1.f - wx) + G[k*3+2].b * wx;
        s0 += wk3[k] * r0;
        s1 += wk3[k] * r1;
        s2 += wk3[k] * r2;
    }
    s0 *= rw; s1 *= rw; s2 *= rw;

    // ---- pair-combine rows, even lane writes ----
    float t0 = s0 + __shfl_xor(s0, 1);
    float t1 = s1 + __shfl_xor(s1, 1);
    float t2 = s2 + __shfl_xor(s2, 1);
    if (h == 0) {
        out[(size_t)p * 3 + 0] = t0;
        out[(size_t)p * 3 + 1] = t1;
        out[(size_t)p * 3 + 2] = t2;
    }
}

extern "C" void kernel_launch(void* const* d_in, const int* in_sizes, int n_in,
                              void* d_out, int out_size, void* d_ws, size_t ws_size,
                              hipStream_t stream) {
    const float* X     = (const float*)d_in[0];
    const float* shots = (const float*)d_in[1];
    const float* lpos  = (const float*)d_in[2];
    float* out = (float*)d_out;
    int B = in_sizes[0] / 4;
    long long T = 2LL * B;                 // 2 threads per point
    int grid = (int)((T + 255) / 256);
    lsf_kernel<<<grid, 256, 0, stream>>>(X, shots, lpos, out, B);
}